// Round 4
// baseline (40.260 us; speedup 1.0000x reference)
//
#include <hip/hip_runtime.h>
#include <hip/hip_bf16.h>

#define T_FRAMES 100
#define R_REP    8
#define N_ATOMS  83
#define N_BINS   120
#define NPAIRS   (N_ATOMS * (N_ATOMS - 1) / 2)   // 3403
#define BLK      256
#define PPT      7          // pairs per thread: 256*7=1792 >= 1702
#define HALF0    1702       // pairs in block-half 0 (half 1 gets 1701)

__device__ __forceinline__ int rowstart(int i) {
    // upper-triangle (i<j) row start for N=83: i*(165-i)/2
    return (i * (165 - i)) >> 1;
}

// ---------------- kernel 1: min-image distances + histogram ----------------
// Two blocks per (frame t, replica r); each handles ~1702 of the 3403 i<j pairs.
__global__ __launch_bounds__(BLK, 1) void rdf_hist_kernel(
        const float* __restrict__ radii,   // [T, R, N, 3]
        const float* __restrict__ cell,    // [3, 3]
        const float* __restrict__ bins,    // [N_BINS+1]
        unsigned int* __restrict__ hist_g) // [R, N_BINS]
{
#pragma clang fp contract(off)
    __shared__ float sx[N_ATOMS], sy[N_ATOMS], sz[N_ATOMS];
    __shared__ float sshift[27][4];        // 16B stride -> ds_read_b128
    __shared__ float sbins[N_BINS + 1];
    __shared__ unsigned int shist[N_BINS];

    const int tid  = threadIdx.x;
    const int blk  = blockIdx.x;           // 0 .. 2*T*R-1
    const int fr   = blk >> 1;             // frame index 0..799
    const int half = blk & 1;
    const int t = fr / R_REP;
    const int r = fr % R_REP;
    const int pstart = half ? HALF0 : 0;
    const int pcount = half ? (NPAIRS - HALF0) : HALF0;

    // stage this frame's atoms (SoA)
    for (int i = tid; i < N_ATOMS; i += BLK) {
        const float* p = radii + (((size_t)t * R_REP + r) * N_ATOMS + i) * 3;
        sx[i] = p[0]; sy[i] = p[1]; sz[i] = p[2];
    }
    for (int i = tid; i <= N_BINS; i += BLK) sbins[i] = bins[i];
    for (int i = tid; i < N_BINS; i += BLK) shist[i] = 0u;

    // 27 periodic-image shifts: combos({-1,0,1}^3) @ cell (fp32 chain as numpy)
    if (tid < 27) {
        float fa = (float)(tid % 3 - 1);
        float fb = (float)((tid / 3) % 3 - 1);
        float fc = (float)(tid / 9 - 1);
        for (int d = 0; d < 3; ++d)
            sshift[tid][d] = (fa * cell[0 * 3 + d] + fb * cell[1 * 3 + d]) + fc * cell[2 * 3 + d];
    }
    __syncthreads();

    // ---- load phase: resolve PPT pairs per thread into registers ----------
    float dx[PPT], dy[PPT], dz[PPT], d2m[PPT];
#pragma unroll
    for (int s = 0; s < PPT; ++s) {
        const int l = tid + s * BLK;               // local pair idx in this half
        const int p = (l < pcount) ? (pstart + l) : 0;   // clamp tail to pair 0
        int i = (int)((165.0f - sqrtf((float)(27225 - 8 * p))) * 0.5f);
        if (i < 0) i = 0;
        if (i > N_ATOMS - 2) i = N_ATOMS - 2;
        while (rowstart(i + 1) <= p) ++i;
        while (rowstart(i) > p) --i;
        const int j = p - rowstart(i) + i + 1;
        dx[s] = sx[i] - sx[j];
        dy[s] = sy[i] - sy[j];
        dz[s] = sz[i] - sz[j];
        d2m[s] = 3.4e38f;
    }

    // ---- fully-unrolled shift loop: 27 x ds_read_b128, then pure VALU -----
#pragma unroll
    for (int k = 0; k < 27; ++k) {
        const float4 sh = *reinterpret_cast<const float4*>(&sshift[k][0]);
#pragma unroll
        for (int s = 0; s < PPT; ++s) {
            const float t0 = dx[s] - sh.x;
            const float t1 = dy[s] - sh.y;
            const float t2 = dz[s] - sh.z;
            const float d2 = (t0 * t0 + t1 * t1) + t2 * t2;  // contract off
            d2m[s] = fminf(d2m[s], d2);
        }
    }

    // ---- binning phase -----------------------------------------------------
    const float b0   = sbins[0];
    const float bmax = sbins[N_BINS];
    const float inv_step = (float)N_BINS / (bmax - b0);
#pragma unroll
    for (int s = 0; s < PPT; ++s) {
        const int l = tid + s * BLK;
        if (l >= pcount) continue;
        const float d = sqrtf(d2m[s]);             // IEEE-correct
        if (d >= b0 && d <= bmax) {
            int idx = (int)((d - b0) * inv_step);
            if (idx > N_BINS - 1) idx = N_BINS - 1;
            if (idx < 0) idx = 0;
            while (idx > 0 && d < sbins[idx]) --idx;
            while (idx < N_BINS - 1 && d >= sbins[idx + 1]) ++idx;
            atomicAdd(&shist[idx], 2u);            // (i,j)/(j,i) bit-identical
        }
    }
    __syncthreads();

    for (int i = tid; i < N_BINS; i += BLK)
        if (shist[i]) atomicAdd(&hist_g[r * N_BINS + i], shist[i]);
}

// ---------------- kernel 2: rdf = hist / Z, maes ---------------------------
__global__ __launch_bounds__(256) void finalize_kernel(
        const unsigned int* __restrict__ hist_g, // [R, N_BINS]
        const float* __restrict__ cell,
        const float* __restrict__ bins,
        const float* __restrict__ gt,            // [N_BINS]
        float* __restrict__ out)                 // [R*N_BINS + R]
{
    __shared__ float srdf[R_REP * N_BINS];
    const int tid = threadIdx.x;

    const float c0x = cell[0], c0y = cell[1], c0z = cell[2];
    const float c1x = cell[3], c1y = cell[4], c1z = cell[5];
    const float c2x = cell[6], c2y = cell[7], c2z = cell[8];
    const float crx = c0y * c1z - c0z * c1y;
    const float cry = c0z * c1x - c0x * c1z;
    const float crz = c0x * c1y - c0y * c1x;
    const float vol = fabsf(crx * c2x + cry * c2y + crz * c2z);
    const float rho = (float)(T_FRAMES * N_ATOMS * N_ATOMS) / vol;
    const float coef = (rho * 1.33333337f) * 3.14159274f;  // rho * 4/3 * pi

    for (int e = tid; e < R_REP * N_BINS; e += 256) {
        const int b = e % N_BINS;
        const float b1 = bins[b], b2 = bins[b + 1];
        const float Z = coef * (b2 * b2 * b2 - b1 * b1 * b1);
        const float v = (float)hist_g[e] / Z;
        out[e] = v;
        srdf[e] = v;
    }
    __syncthreads();

    if (tid < R_REP) {
        float s = 0.f;
        for (int b = 0; b < N_BINS; ++b)
            s += fabsf(srdf[tid * N_BINS + b] - gt[b]);
        out[R_REP * N_BINS + tid] = 6.0f * (s * (1.0f / (float)N_BINS));
    }
}

extern "C" void kernel_launch(void* const* d_in, const int* in_sizes, int n_in,
                              void* d_out, int out_size, void* d_ws, size_t ws_size,
                              hipStream_t stream) {
    const float* radii = (const float*)d_in[0];  // [100,8,83,3]
    const float* cell  = (const float*)d_in[1];  // [3,3]
    const float* gt    = (const float*)d_in[2];  // [120]
    const float* bins  = (const float*)d_in[3];  // [121]
    float* out = (float*)d_out;                  // 8*120 rdfs + 8 maes
    unsigned int* hist = (unsigned int*)d_ws;    // R*N_BINS u32

    hipMemsetAsync(hist, 0, R_REP * N_BINS * sizeof(unsigned int), stream);
    hipLaunchKernelGGL(rdf_hist_kernel, dim3(2 * T_FRAMES * R_REP), dim3(BLK), 0, stream,
                       radii, cell, bins, hist);
    hipLaunchKernelGGL(finalize_kernel, dim3(1), dim3(256), 0, stream,
                       hist, cell, bins, gt, out);
}

// Round 5
// 33.507 us; speedup vs baseline: 1.2015x; 1.2015x over previous
//
#include <hip/hip_runtime.h>

#define T_FRAMES 100
#define R_REP    8
#define N_ATOMS  83
#define N_BINS   120
#define NPAIRS   (N_ATOMS * (N_ATOMS - 1) / 2)   // 3403
#define BLK      256
#define PPT      7          // pairs per thread: 256*7=1792 >= 1702
#define HALF0    1702       // pairs in block-half 0 (half 1 gets 1701)
#define SLOTS_PER_REP (2 * T_FRAMES)             // 200 partial hists per replica

__device__ __forceinline__ int rowstart(int i) {
    // upper-triangle (i<j) row start for N=83: i*(165-i)/2
    return (i * (165 - i)) >> 1;
}

// ---------------- kernel 1: min-image distances + per-block partial hist ---
// Two blocks per (frame t, replica r). Writes partial[slot][bin], slot r-major.
__global__ __launch_bounds__(BLK) void rdf_hist_kernel(
        const float* __restrict__ radii,    // [T, R, N, 3]
        const float* __restrict__ cell,     // [3, 3]
        const float* __restrict__ bins,     // [N_BINS+1]
        unsigned int* __restrict__ partial) // [R, SLOTS_PER_REP, N_BINS]
{
#pragma clang fp contract(off)
    __shared__ float sx[N_ATOMS], sy[N_ATOMS], sz[N_ATOMS];
    __shared__ float sshift[28][4];        // 16B stride; row 27 = zero pad
    __shared__ float sbins[N_BINS + 1];
    __shared__ unsigned int shist[N_BINS];

    const int tid  = threadIdx.x;
    const int blk  = blockIdx.x;           // 0 .. 2*T*R-1
    const int fr   = blk >> 1;             // frame index 0..799
    const int half = blk & 1;
    const int t = fr / R_REP;
    const int r = fr % R_REP;
    const int pstart = half ? HALF0 : 0;
    const int pcount = half ? (NPAIRS - HALF0) : HALF0;

    // stage this frame's atoms (SoA)
    for (int i = tid; i < N_ATOMS; i += BLK) {
        const float* p = radii + (((size_t)t * R_REP + r) * N_ATOMS + i) * 3;
        sx[i] = p[0]; sy[i] = p[1]; sz[i] = p[2];
    }
    for (int i = tid; i <= N_BINS; i += BLK) sbins[i] = bins[i];
    for (int i = tid; i < N_BINS; i += BLK) shist[i] = 0u;

    // 27 periodic-image shifts: combos({-1,0,1}^3) @ cell (fp32 chain as numpy)
    if (tid < 28) {
        if (tid < 27) {
            float fa = (float)(tid % 3 - 1);
            float fb = (float)((tid / 3) % 3 - 1);
            float fc = (float)(tid / 9 - 1);
            for (int d = 0; d < 3; ++d)
                sshift[tid][d] = (fa * cell[0 * 3 + d] + fb * cell[1 * 3 + d]) + fc * cell[2 * 3 + d];
            sshift[tid][3] = 0.f;
        } else {
            sshift[27][0] = sshift[27][1] = sshift[27][2] = sshift[27][3] = 0.f;
        }
    }
    __syncthreads();

    // ---- load phase: resolve PPT pairs per thread into registers ----------
    float dx[PPT], dy[PPT], dz[PPT], d2m[PPT];
#pragma unroll
    for (int s = 0; s < PPT; ++s) {
        const int l = tid + s * BLK;               // local pair idx in this half
        const int p = (l < pcount) ? (pstart + l) : 0;   // clamp tail to pair 0
        int i = (int)((165.0f - sqrtf((float)(27225 - 8 * p))) * 0.5f);
        if (i < 0) i = 0;
        if (i > N_ATOMS - 2) i = N_ATOMS - 2;
        while (rowstart(i + 1) <= p) ++i;
        while (rowstart(i) > p) --i;
        const int j = p - rowstart(i) + i + 1;
        dx[s] = sx[i] - sx[j];
        dy[s] = sy[i] - sy[j];
        dz[s] = sz[i] - sz[j];
        d2m[s] = 3.4e38f;
    }

    // ---- rolled shift loop with explicit next-shift prefetch --------------
    float4 sh = *reinterpret_cast<const float4*>(&sshift[0][0]);
#pragma unroll 1
    for (int k = 0; k < 27; ++k) {
        const float4 nxt = *reinterpret_cast<const float4*>(&sshift[k + 1][0]);
#pragma unroll
        for (int s = 0; s < PPT; ++s) {
            const float t0 = dx[s] - sh.x;
            const float t1 = dy[s] - sh.y;
            const float t2 = dz[s] - sh.z;
            const float d2 = (t0 * t0 + t1 * t1) + t2 * t2;  // contract off
            d2m[s] = fminf(d2m[s], d2);
        }
        sh = nxt;
    }

    // ---- binning phase -----------------------------------------------------
    const float b0   = sbins[0];
    const float bmax = sbins[N_BINS];
    const float inv_step = (float)N_BINS / (bmax - b0);
#pragma unroll
    for (int s = 0; s < PPT; ++s) {
        const int l = tid + s * BLK;
        if (l >= pcount) continue;
        const float d = sqrtf(d2m[s]);             // IEEE-correct
        if (d >= b0 && d <= bmax) {
            int idx = (int)((d - b0) * inv_step);
            if (idx > N_BINS - 1) idx = N_BINS - 1;
            if (idx < 0) idx = 0;
            while (idx > 0 && d < sbins[idx]) --idx;
            while (idx < N_BINS - 1 && d >= sbins[idx + 1]) ++idx;
            atomicAdd(&shist[idx], 2u);            // (i,j)/(j,i) bit-identical
        }
    }
    __syncthreads();

    // ---- flush partial hist (plain stores; no zeroed global needed) -------
    unsigned int* dst = partial + ((size_t)(r * T_FRAMES + t) * 2 + half) * N_BINS;
    for (int b = tid; b < N_BINS; b += BLK) dst[b] = shist[b];
}

// ---------------- kernel 2: reduce partials, rdf = hist/Z, maes ------------
// One block per replica. 256 threads.
__global__ __launch_bounds__(256) void finalize_kernel(
        const unsigned int* __restrict__ partial, // [R, SLOTS_PER_REP, N_BINS]
        const float* __restrict__ cell,
        const float* __restrict__ bins,
        const float* __restrict__ gt,             // [N_BINS]
        float* __restrict__ out)                  // [R*N_BINS + R]
{
    __shared__ unsigned int ssum[2][N_BINS];
    __shared__ float sdiff[N_BINS];
    const int r = blockIdx.x;
    const int tid = threadIdx.x;
    const int h = tid >> 7;          // 0 or 1: which 100-slot half
    const int b = tid & 127;

    if (b < N_BINS) {
        const unsigned int* base = partial
            + (size_t)r * SLOTS_PER_REP * N_BINS + (size_t)h * 100 * N_BINS + b;
        unsigned int acc = 0;
#pragma unroll 20
        for (int f = 0; f < 100; ++f) acc += base[(size_t)f * N_BINS];
        ssum[h][b] = acc;
    }
    __syncthreads();

    const float c0x = cell[0], c0y = cell[1], c0z = cell[2];
    const float c1x = cell[3], c1y = cell[4], c1z = cell[5];
    const float c2x = cell[6], c2y = cell[7], c2z = cell[8];
    const float crx = c0y * c1z - c0z * c1y;
    const float cry = c0z * c1x - c0x * c1z;
    const float crz = c0x * c1y - c0y * c1x;
    const float vol = fabsf(crx * c2x + cry * c2y + crz * c2z);
    const float rho = (float)(T_FRAMES * N_ATOMS * N_ATOMS) / vol;
    const float coef = (rho * 1.33333337f) * 3.14159274f;  // rho * 4/3 * pi

    if (tid < N_BINS) {
        const unsigned int tot = ssum[0][tid] + ssum[1][tid];
        const float b1 = bins[tid], b2 = bins[tid + 1];
        const float Z = coef * (b2 * b2 * b2 - b1 * b1 * b1);
        const float v = (float)tot / Z;
        out[r * N_BINS + tid] = v;
        sdiff[tid] = fabsf(v - gt[tid]);
    }
    __syncthreads();

    if (tid < 64) {
        float s = sdiff[tid] + ((tid < N_BINS - 64) ? sdiff[tid + 64] : 0.0f);
#pragma unroll
        for (int off = 32; off; off >>= 1) s += __shfl_down(s, off, 64);
        if (tid == 0)
            out[R_REP * N_BINS + r] = 6.0f * (s * (1.0f / (float)N_BINS));
    }
}

extern "C" void kernel_launch(void* const* d_in, const int* in_sizes, int n_in,
                              void* d_out, int out_size, void* d_ws, size_t ws_size,
                              hipStream_t stream) {
    const float* radii = (const float*)d_in[0];  // [100,8,83,3]
    const float* cell  = (const float*)d_in[1];  // [3,3]
    const float* gt    = (const float*)d_in[2];  // [120]
    const float* bins  = (const float*)d_in[3];  // [121]
    float* out = (float*)d_out;                  // 8*120 rdfs + 8 maes
    unsigned int* part = (unsigned int*)d_ws;    // [8][200][120] u32 = 750 KB

    hipLaunchKernelGGL(rdf_hist_kernel, dim3(2 * T_FRAMES * R_REP), dim3(BLK), 0, stream,
                       radii, cell, bins, part);
    hipLaunchKernelGGL(finalize_kernel, dim3(R_REP), dim3(256), 0, stream,
                       part, cell, bins, gt, out);
}

// Round 6
// 27.692 us; speedup vs baseline: 1.4538x; 1.2100x over previous
//
#include <hip/hip_runtime.h>

#define T_FRAMES 100
#define R_REP    8
#define N_ATOMS  83
#define N_BINS   120
#define NPAIRS   (N_ATOMS * (N_ATOMS - 1) / 2)   // 3403
#define BLK      256
#define PPT      7          // pairs per thread: 256*7=1792 >= 1702
#define HALF0    1702       // pairs in block-half 0 (half 1 gets 1701)
#define SLOTS_PER_REP (2 * T_FRAMES)             // 200 partial hists per replica

__device__ __forceinline__ int rowstart(int i) {
    // upper-triangle (i<j) row start for N=83: i*(165-i)/2
    return (i * (165 - i)) >> 1;
}

// ---------------- kernel 1: min-image distances + per-block partial hist ---
// Two blocks per (frame t, replica r). 8-candidate exact min-image search:
// argmin over the 27-box provably lies in {floor(f~),floor(f~)+1}^3 (curvature
// ~104 A^2 vs coupling ~4 A^2); each candidate d2 uses the reference's exact
// fp32 chain, so min over 8 == min over 27 bit-exactly.
__global__ __launch_bounds__(BLK, 4) void rdf_hist_kernel(
        const float* __restrict__ radii,    // [T, R, N, 3]
        const float* __restrict__ cell,     // [3, 3]
        const float* __restrict__ bins,     // [N_BINS+1]
        unsigned int* __restrict__ partial) // [R, SLOTS_PER_REP, N_BINS]
{
#pragma clang fp contract(off)
    __shared__ float sx[N_ATOMS], sy[N_ATOMS], sz[N_ATOMS];
    __shared__ float scell[12];            // rows padded to 4
    __shared__ float sbins[N_BINS + 1];
    __shared__ unsigned int shist[N_BINS];

    const int tid  = threadIdx.x;
    const int blk  = blockIdx.x;           // 0 .. 2*T*R-1
    const int fr   = blk >> 1;             // frame index 0..799
    const int half = blk & 1;
    const int t = fr / R_REP;
    const int r = fr % R_REP;
    const int pstart = half ? HALF0 : 0;
    const int pcount = half ? (NPAIRS - HALF0) : HALF0;

    // stage this frame's atoms (SoA)
    for (int i = tid; i < N_ATOMS; i += BLK) {
        const float* p = radii + (((size_t)t * R_REP + r) * N_ATOMS + i) * 3;
        sx[i] = p[0]; sy[i] = p[1]; sz[i] = p[2];
    }
    for (int i = tid; i <= N_BINS; i += BLK) sbins[i] = bins[i];
    for (int i = tid; i < N_BINS; i += BLK) shist[i] = 0u;
    if (tid < 9) scell[(tid / 3) * 4 + (tid % 3)] = cell[tid];
    __syncthreads();

    // cell rows -> registers (broadcast reads)
    float cc[3][3];
#pragma unroll
    for (int q = 0; q < 3; ++q)
#pragma unroll
        for (int d = 0; d < 3; ++d) cc[q][d] = scell[q * 4 + d];
    // reciprocal row-norms (selection only; precision irrelevant)
    float rn[3];
#pragma unroll
    for (int q = 0; q < 3; ++q)
        rn[q] = 1.0f / (cc[q][0] * cc[q][0] + cc[q][1] * cc[q][1] + cc[q][2] * cc[q][2]);

    // ---- load phase: resolve PPT pairs per thread into registers ----------
    float dx[PPT], dy[PPT], dz[PPT], d2m[PPT];
#pragma unroll
    for (int s = 0; s < PPT; ++s) {
        const int l = tid + s * BLK;               // local pair idx in this half
        const int p = (l < pcount) ? (pstart + l) : 0;   // clamp tail to pair 0
        int i = (int)((165.0f - sqrtf((float)(27225 - 8 * p))) * 0.5f);
        if (i < 0) i = 0;
        if (i > N_ATOMS - 2) i = N_ATOMS - 2;
        while (rowstart(i + 1) <= p) ++i;
        while (rowstart(i) > p) --i;
        const int j = p - rowstart(i) + i + 1;
        dx[s] = sx[i] - sx[j];
        dy[s] = sy[i] - sy[j];
        dz[s] = sz[i] - sz[j];
        d2m[s] = 3.4e38f;
    }

    // ---- 8-candidate exact min-image, pure register math ------------------
#pragma unroll
    for (int s = 0; s < PPT; ++s) {
        const float Dx = dx[s], Dy = dy[s], Dz = dz[s];
        // per-axis projection (approximate fractional coordinate)
        const float fx = (Dx * cc[0][0] + Dy * cc[0][1] + Dz * cc[0][2]) * rn[0];
        const float fy = (Dx * cc[1][0] + Dy * cc[1][1] + Dz * cc[1][2]) * rn[1];
        const float fz = (Dx * cc[2][0] + Dy * cc[2][1] + Dz * cc[2][2]) * rn[2];
        int axi = (int)floorf(fx); axi = axi < -1 ? -1 : (axi > 0 ? 0 : axi);
        int ayi = (int)floorf(fy); ayi = ayi < -1 ? -1 : (ayi > 0 ? 0 : ayi);
        int azi = (int)floorf(fz); azi = azi < -1 ? -1 : (azi > 0 ? 0 : azi);
        const float na0 = (float)axi, na1 = na0 + 1.0f;   // in {-1,0},{0,1}
        const float nb0 = (float)ayi, nb1 = nb0 + 1.0f;
        const float nc0 = (float)azi, nc1 = nc0 + 1.0f;

        // exact products n*cell_row (x +-1.0/0.0 is exact)
        float An[2][3], Bn[2][3], Cn[2][3];
#pragma unroll
        for (int d = 0; d < 3; ++d) {
            An[0][d] = na0 * cc[0][d]; An[1][d] = na1 * cc[0][d];
            Bn[0][d] = nb0 * cc[1][d]; Bn[1][d] = nb1 * cc[1][d];
            Cn[0][d] = nc0 * cc[2][d]; Cn[1][d] = nc1 * cc[2][d];
        }
        float m = d2m[s];
#pragma unroll
        for (int ia = 0; ia < 2; ++ia) {
#pragma unroll
            for (int ib = 0; ib < 2; ++ib) {
                // (na*c0d + nb*c1d) : reference's first add
                const float m0 = An[ia][0] + Bn[ib][0];
                const float m1 = An[ia][1] + Bn[ib][1];
                const float m2 = An[ia][2] + Bn[ib][2];
#pragma unroll
                for (int ic = 0; ic < 2; ++ic) {
                    // + nc*c2d : reference's second add -> exact shift value
                    const float t0 = Dx - (m0 + Cn[ic][0]);
                    const float t1 = Dy - (m1 + Cn[ic][1]);
                    const float t2 = Dz - (m2 + Cn[ic][2]);
                    const float d2 = (t0 * t0 + t1 * t1) + t2 * t2;  // contract off
                    m = fminf(m, d2);
                }
            }
        }
        d2m[s] = m;
    }

    // ---- binning phase -----------------------------------------------------
    const float blo  = sbins[0];
    const float bhi  = sbins[N_BINS];
    const float inv_step = (float)N_BINS / (bhi - blo);
#pragma unroll
    for (int s = 0; s < PPT; ++s) {
        const int l = tid + s * BLK;
        if (l >= pcount) continue;
        const float d = sqrtf(d2m[s]);             // IEEE-correct
        if (d >= blo && d <= bhi) {
            int idx = (int)((d - blo) * inv_step);
            if (idx > N_BINS - 1) idx = N_BINS - 1;
            if (idx < 0) idx = 0;
            while (idx > 0 && d < sbins[idx]) --idx;
            while (idx < N_BINS - 1 && d >= sbins[idx + 1]) ++idx;
            atomicAdd(&shist[idx], 2u);            // (i,j)/(j,i) bit-identical
        }
    }
    __syncthreads();

    // ---- flush partial hist (plain stores; no zeroed global needed) -------
    unsigned int* dst = partial + ((size_t)(r * T_FRAMES + t) * 2 + half) * N_BINS;
    for (int b = tid; b < N_BINS; b += BLK) dst[b] = shist[b];
}

// ---------------- kernel 2: reduce partials, rdf = hist/Z, maes ------------
// One block per replica. 256 threads.
__global__ __launch_bounds__(256) void finalize_kernel(
        const unsigned int* __restrict__ partial, // [R, SLOTS_PER_REP, N_BINS]
        const float* __restrict__ cell,
        const float* __restrict__ bins,
        const float* __restrict__ gt,             // [N_BINS]
        float* __restrict__ out)                  // [R*N_BINS + R]
{
    __shared__ unsigned int ssum[2][N_BINS];
    __shared__ float sdiff[N_BINS];
    const int r = blockIdx.x;
    const int tid = threadIdx.x;
    const int h = tid >> 7;          // 0 or 1: which 100-slot half
    const int b = tid & 127;

    if (b < N_BINS) {
        const unsigned int* base = partial
            + (size_t)r * SLOTS_PER_REP * N_BINS + (size_t)h * 100 * N_BINS + b;
        unsigned int acc = 0;
#pragma unroll 20
        for (int f = 0; f < 100; ++f) acc += base[(size_t)f * N_BINS];
        ssum[h][b] = acc;
    }
    __syncthreads();

    const float c0x = cell[0], c0y = cell[1], c0z = cell[2];
    const float c1x = cell[3], c1y = cell[4], c1z = cell[5];
    const float c2x = cell[6], c2y = cell[7], c2z = cell[8];
    const float crx = c0y * c1z - c0z * c1y;
    const float cry = c0z * c1x - c0x * c1z;
    const float crz = c0x * c1y - c0y * c1x;
    const float vol = fabsf(crx * c2x + cry * c2y + crz * c2z);
    const float rho = (float)(T_FRAMES * N_ATOMS * N_ATOMS) / vol;
    const float coef = (rho * 1.33333337f) * 3.14159274f;  // rho * 4/3 * pi

    if (tid < N_BINS) {
        const unsigned int tot = ssum[0][tid] + ssum[1][tid];
        const float b1 = bins[tid], b2 = bins[tid + 1];
        const float Z = coef * (b2 * b2 * b2 - b1 * b1 * b1);
        const float v = (float)tot / Z;
        out[r * N_BINS + tid] = v;
        sdiff[tid] = fabsf(v - gt[tid]);
    }
    __syncthreads();

    if (tid < 64) {
        float s = sdiff[tid] + ((tid < N_BINS - 64) ? sdiff[tid + 64] : 0.0f);
#pragma unroll
        for (int off = 32; off; off >>= 1) s += __shfl_down(s, off, 64);
        if (tid == 0)
            out[R_REP * N_BINS + r] = 6.0f * (s * (1.0f / (float)N_BINS));
    }
}

extern "C" void kernel_launch(void* const* d_in, const int* in_sizes, int n_in,
                              void* d_out, int out_size, void* d_ws, size_t ws_size,
                              hipStream_t stream) {
    const float* radii = (const float*)d_in[0];  // [100,8,83,3]
    const float* cell  = (const float*)d_in[1];  // [3,3]
    const float* gt    = (const float*)d_in[2];  // [120]
    const float* bins  = (const float*)d_in[3];  // [121]
    float* out = (float*)d_out;                  // 8*120 rdfs + 8 maes
    unsigned int* part = (unsigned int*)d_ws;    // [8][200][120] u32 = 750 KB

    hipLaunchKernelGGL(rdf_hist_kernel, dim3(2 * T_FRAMES * R_REP), dim3(BLK), 0, stream,
                       radii, cell, bins, part);
    hipLaunchKernelGGL(finalize_kernel, dim3(R_REP), dim3(256), 0, stream,
                       part, cell, bins, gt, out);
}